// Round 4
// baseline (145.369 us; speedup 1.0000x reference)
//
#include <hip/hip_runtime.h>
#include <math.h>

// -------------------------------------------------------------------------
// UpperBandEntropyLoss16: 16x16 block DCT -> upper band (128 coeffs)
// -> adaptive threshold -> L2 normalize -> mean entropy (scalar out).
//
// R3 -> R4: (1) scattered 16B/lane global gathers (32 partial cachelines
// per instr) replaced with coalesced per-wave staging (8 full lines/instr)
// through XOR-swizzled LDS; stage-1 reads rows back as ds_read_b128.
// Still barrier-free: wave lockstep + in-order DS pipe allow read->overlay
// -write on the same 4KB region after lgkmcnt(0). (2) Entropy phase is now
// fully in-register (stage-2 keeps c[16] in VGPRs; band selected by mask;
// 12 shfl_xor) -- no band-pack LDS writes, no entropy LDS reads, one fewer
// phase on the per-wave critical path.
// -------------------------------------------------------------------------

constexpr double kPi = 3.14159265358979323846;

// constexpr cosine (double): range-reduce + Taylor, applied to the
// float32-rounded argument to match numpy's f32 HARM construction.
constexpr double ccos(double x) {
    while (x > kPi) x -= 2.0 * kPi;
    while (x < -kPi) x += 2.0 * kPi;
    double x2 = x * x;
    double term = 1.0, sum = 1.0;
    for (int k = 1; k <= 24; ++k) {
        term *= -x2 / (double)((2 * k - 1) * (2 * k));
        sum += term;
    }
    return sum;
}

struct DctTables {
    // Indexed [spatial][freq]; normalization folded into freq index.
    float g1[16][16];  // H[j][v] * n_v            (stage 1, row DCT)
    float g2[16][16];  // H[i][u] * n_u * SCALE    (stage 2, col DCT)
    constexpr DctTables() : g1{}, g2{} {
        for (int j = 0; j < 16; ++j) {
            for (int f = 0; f < 16; ++f) {
                float colf = (float)((double)f * kPi) / 32.0f;
                float arg = (2.0f * (float)j + 1.0f) * colf;
                float h = (float)ccos((double)arg);
                float n = (f == 0) ? 0.70710678118654752440f : 1.0f;
                g1[j][f] = h * n;
                g2[j][f] = h * n * 0.17677669529663688110f;  // 1/sqrt(32)
            }
        }
    }
};
constexpr DctTables kT;

#define NWG 6144
#define NPART (NWG * 4)

// Intra-wave phase boundary: HW lockstep + in-order LDS pipe give ordering;
// the waitcnt+clobber stops the compiler from hoisting reads over writes.
#define WAVE_LDS_FENCE() asm volatile("s_waitcnt lgkmcnt(0)" ::: "memory")

__global__ __launch_bounds__(256, 8) void dct_entropy_kernel(
    const float* __restrict__ x, float* __restrict__ partials) {
    __shared__ float smem[4096];  // 4 waves x 1024 floats (16 KB)

    const int t = threadIdx.x;
    const int wave = t >> 6;
    const int lane = t & 63;
    const int b = lane >> 4;   // block within wave (0..3)
    const int il = lane & 15;  // stage1: row i; stage2: freq v
    float* R = smem + (wave << 10);

    const int g = blockIdx.x;
    const int bc = g >> 8;         // 0..23  (b*c)
    const int br = (g >> 2) & 63;  // block row
    const int cg = g & 3;          // 256-col group
    // wave's 16x64 strip base
    const float* gbase =
        x + ((size_t)bc << 20) + ((size_t)br << 14) + (cg << 8) + (wave << 6);

    // ---- coalesced load: instr k covers rows 4k..4k+3, 256B per row ----
    float4 v4[4];
    {
        const int r0 = lane >> 4;      // row within group of 4
        const int ch = lane & 15;      // float4 chunk within row
#pragma unroll
        for (int k = 0; k < 4; ++k) {
            v4[k] = *(const float4*)(gbase + (size_t)(4 * k + r0) * 1024 +
                                     ch * 4);
        }
        // stage to LDS, XOR-swizzled: logical chunk ch of row r at ch^r
#pragma unroll
        for (int k = 0; k < 4; ++k) {
            const int r = 4 * k + r0;
            *(float4*)(&R[(r << 6) + ((ch ^ r) << 2)]) = v4[k];
        }
    }
    WAVE_LDS_FENCE();

    // ---- stage 1: lane (b, i=il) reads row i of block b (4 chunks) ----
    float xr[16];
#pragma unroll
    for (int tt = 0; tt < 4; ++tt) {
        const int ch = 4 * b + tt;
        float4 ld = *(const float4*)(&R[(il << 6) + ((ch ^ il) << 2)]);
        xr[4 * tt + 0] = ld.x;
        xr[4 * tt + 1] = ld.y;
        xr[4 * tt + 2] = ld.z;
        xr[4 * tt + 3] = ld.w;
    }
    WAVE_LDS_FENCE();  // reads landed in regs; safe to overlay-write below

    // row DCT -> transposed, XOR-swizzled write (same chunk^row scheme):
    // logical (row v, col b*16+il) -> chunk cc=4b+(il>>2), word il&3.
    {
        const int cc = (b << 2) + (il >> 2);
        const int lo = il & 3;
#pragma unroll
        for (int v = 0; v < 16; ++v) {
            float acc = 0.0f;
#pragma unroll
            for (int j = 0; j < 16; ++j) acc = fmaf(xr[j], kT.g1[j][v], acc);
            R[(v << 6) + ((cc ^ v) << 2) + lo] = acc;
        }
    }
    WAVE_LDS_FENCE();

    // ---- stage 2: lane (b, v=il) reads 16 cols of row v; c[16] in regs ----
    float ti[16];
#pragma unroll
    for (int tt = 0; tt < 4; ++tt) {
        const int ch = 4 * b + tt;
        float4 ld = *(const float4*)(&R[(il << 6) + ((ch ^ il) << 2)]);
        ti[4 * tt + 0] = ld.x;
        ti[4 * tt + 1] = ld.y;
        ti[4 * tt + 2] = ld.z;
        ti[4 * tt + 3] = ld.w;
    }
    WAVE_LDS_FENCE();

    float c[16];
#pragma unroll
    for (int u = 0; u < 16; ++u) {
        float acc = 0.0f;
#pragma unroll
        for (int i = 0; i < 16; ++i) acc = fmaf(ti[i], kT.g2[i][u], acc);
        c[u] = acc;
    }

    // ---- entropy, fully in-register ----
    // Band for column v: u >= u_min, u_min = 15-v (v<=7) else 16-v.
    const int v = il;
    const int u_min = (v > 7) ? (16 - v) : (15 - v);

    float s = 0.0f;
#pragma unroll
    for (int u = 0; u < 16; ++u) s += (u >= u_min) ? c[u] : 0.0f;
#pragma unroll
    for (int m = 1; m <= 8; m <<= 1) s += __shfl_xor(s, m);
    const float mean = s * (1.0f / 128.0f);

    float a[16];
    float sq = 0.0f;
#pragma unroll
    for (int u = 0; u < 16; ++u) {
        float au = (c[u] < mean) ? 1e-12f : (fabsf(c[u]) + 1e-12f);
        a[u] = (u >= u_min) ? au : 0.0f;
        sq = fmaf(a[u], a[u], sq);
    }
#pragma unroll
    for (int m = 1; m <= 8; m <<= 1) sq += __shfl_xor(sq, m);
    const float inv = 1.0f / fmaxf(sqrtf(sq), 1e-12f);

    float e = 0.0f;
#pragma unroll
    for (int u = 0; u < 16; ++u) {
        float p = a[u] * inv;
        float term = p * __log2f(p);
        e += (u >= u_min) ? term : 0.0f;  // masked-out lanes: p=0 -> skip
    }
    // reduce within block (xor 1..8), then across the wave's 4 blocks
#pragma unroll
    for (int m = 1; m <= 32; m <<= 1) e += __shfl_xor(e, m);
    if (lane == 0) partials[(g << 2) + wave] = e;
}

__global__ __launch_bounds__(1024) void reduce_partials(
    const float* __restrict__ partials, float* __restrict__ out) {
    __shared__ float s[16];
    float v = 0.0f;
    const float4* p4 = (const float4*)partials;
    for (int i = threadIdx.x; i < NPART / 4; i += 1024) {
        float4 f = p4[i];
        v += (f.x + f.y) + (f.z + f.w);
    }
#pragma unroll
    for (int m = 1; m <= 32; m <<= 1) v += __shfl_xor(v, m);
    if ((threadIdx.x & 63) == 0) s[threadIdx.x >> 6] = v;
    __syncthreads();
    if (threadIdx.x < 16) {
        float tot = s[threadIdx.x];
#pragma unroll
        for (int m = 1; m <= 8; m <<= 1) tot += __shfl_xor(tot, m);
        if (threadIdx.x == 0) out[0] = tot * (-1.0f / 98304.0f);
    }
}

extern "C" void kernel_launch(void* const* d_in, const int* in_sizes, int n_in,
                              void* d_out, int out_size, void* d_ws,
                              size_t ws_size, hipStream_t stream) {
    const float* x = (const float*)d_in[0];
    float* out = (float*)d_out;
    float* ws = (float*)d_ws;  // 24576 per-wave partials
    dct_entropy_kernel<<<NWG, 256, 0, stream>>>(x, ws);
    reduce_partials<<<1, 1024, 0, stream>>>(ws, out);
}

// Round 7
// 144.265 us; speedup vs baseline: 1.0077x; 1.0077x over previous
//
#include <hip/hip_runtime.h>
#include <stdint.h>

// -------------------------------------------------------------------------
// UpperBandEntropyLoss16 via MFMA.
//
// R4 -> R5: the invariant ~45us across R2-R4 was VALU-issue-bound scalar DCT
// (512 FMA/lane). Rewritten on the matrix pipe:
//   coeff = Hn_u^T (X Hn_v)  (commuted so stage-A's A-operand = X row-major,
//   which the MFMA A-fragment layout reads straight from coalesced loads).
// Stage A: W = X * G  : A-frag = X[i][32c+8q..+8) (2xfloat4/lane, full-line
//   coalesced), B = const [G;0] / [0;G] bf16 fragments (block-half select).
// Transpose: W (C-layout) -> B-layout via tiny LDS round trip
//   (4x ds_write_b64 + 4x ds_read_b128, <=2-way banks = free).
// Stage B: C = Gu * W with constant zero-padded A-frag.
// Entropy: R4's verified code, one coeff-column per lane.
// R6 fix: stage-B B-frag read for k>=16 touched never-written LDS slack;
// stale bits forming bf16 NaN gave 0*NaN=NaN in the MFMA dot. Upper K half
// now re-reads the lower half (finite duplicates x A2's exact zeros = 0).
// -------------------------------------------------------------------------

typedef float f32x4 __attribute__((ext_vector_type(4)));
typedef short bf16x8 __attribute__((ext_vector_type(8)));

constexpr double kPi = 3.14159265358979323846;

constexpr double ccos(double x) {
    while (x > kPi) x -= 2.0 * kPi;
    while (x < -kPi) x += 2.0 * kPi;
    double x2 = x * x;
    double term = 1.0, sum = 1.0;
    for (int k = 1; k <= 24; ++k) {
        term *= -x2 / (double)((2 * k - 1) * (2 * k));
        sum += term;
    }
    return sum;
}

// HARM[i][f] = cos((2i+1) * f*pi/32), f32-rounded like numpy's build.
constexpr float fharm(int i, int f) {
    float colf = (float)((double)f * kPi) / 32.0f;
    float arg = (2.0f * (float)i + 1.0f) * colf;
    return (float)ccos((double)arg);
}

constexpr uint16_t f2bf(float f) {
    unsigned u = __builtin_bit_cast(unsigned, f);
    return (uint16_t)((u + 0x7fffu + ((u >> 16) & 1u)) >> 16);
}

// MFMA 16x16x32 fragment layouts (gfx950, HW-verified in guide):
//   A[m = lane&15][k = (lane>>4)*8 + j]   (8 bf16 / lane)
//   B[k = (lane>>4)*8 + j][n = lane&15]
//   C/D: col = lane&15, row = (lane>>4)*4 + reg
struct FragTables {
    alignas(16) uint32_t blo[64][4];  // B = [G2n ; 0]   (selects K lower half)
    alignas(16) uint32_t bhi[64][4];  // B = [0 ; G2n]   (selects K upper half)
    alignas(16) uint32_t a2[64][4];   // A = [Gu | 0],  Gu[u][i]=H[i][u]*n_u*S
    constexpr FragTables() : blo{}, bhi{}, a2{} {
        for (int l = 0; l < 64; ++l) {
            const int n = l & 15;  // B: freq col v ; A2: freq row u
            const int q = l >> 4;
            uint16_t slo[8] = {}, shi[8] = {}, sa[8] = {};
            for (int s = 0; s < 8; ++s) {
                const int k = 8 * q + s;
                if (k < 16) {
                    // G2n[k][n] = H[k][n]*n_n ; Gu[n][k] = H[k][n]*n_n*SCALE
                    float g = fharm(k, n) *
                              ((n == 0) ? 0.70710678118654752440f : 1.0f);
                    slo[s] = f2bf(g);
                    sa[s] = f2bf(g * 0.17677669529663688110f);  // 1/sqrt(32)
                } else {
                    float g = fharm(k - 16, n) *
                              ((n == 0) ? 0.70710678118654752440f : 1.0f);
                    shi[s] = f2bf(g);
                }
            }
            for (int d = 0; d < 4; ++d) {
                blo[l][d] = (uint32_t)slo[2 * d] | ((uint32_t)slo[2 * d + 1] << 16);
                bhi[l][d] = (uint32_t)shi[2 * d] | ((uint32_t)shi[2 * d + 1] << 16);
                a2[l][d] = (uint32_t)sa[2 * d] | ((uint32_t)sa[2 * d + 1] << 16);
            }
        }
    }
};
__constant__ FragTables kF{};

#define NWG 6144
#define NPART (NWG * 4)

// Intra-wave phase boundary: HW lockstep + in-order DS pipe give ordering;
// the waitcnt+clobber stops the compiler from reordering across it.
#define WAVE_LDS_FENCE() asm volatile("s_waitcnt lgkmcnt(0)" ::: "memory")

// bf16 round-to-nearest-even pack, pure integer (matches _rn for non-NaN).
__device__ __forceinline__ uint32_t bfr(float f) {
    uint32_t u = __float_as_uint(f);
    return (u + 0x7fffu + ((u >> 16) & 1u)) >> 16;
}
__device__ __forceinline__ uint32_t pk2(float a, float b) {
    return bfr(a) | (bfr(b) << 16);
}

__global__ __launch_bounds__(256, 4) void dct_entropy_kernel(
    const float* __restrict__ x, float* __restrict__ partials) {
    // per-wave region: 1344 dwords (W_cm 768 + Ccm 1296 overlaid, + slack)
    __shared__ float smem[4 * 1344];

    const int t = threadIdx.x;
    const int wave = t >> 6;
    const int lane = t & 63;
    const int l15 = lane & 15;  // A-row i / D-col v / entropy col
    const int q = lane >> 4;
    float* R = smem + wave * 1344;
    uint32_t* Rw = (uint32_t*)R;

    const int g = blockIdx.x;
    const int bc = g >> 8;         // 0..23 (b*c)
    const int br = (g >> 2) & 63;  // block row
    const int cg = g & 3;          // 256-col group
    const float* gbase =
        x + ((size_t)bc << 20) + ((size_t)br << 14) + (cg << 8) + (wave << 6);

    // ---- A-frags: lane reads X[i=l15][32c + 8q + 0..7], c=0,1 ----
    // Per instr: 16 rows x 4 lanes x 16B; lo+hi pairs consume full 128B lines.
    const float* rp = gbase + (size_t)l15 * 1024 + 8 * q;
    float4 lo0 = *(const float4*)(rp);
    float4 hi0 = *(const float4*)(rp + 4);
    float4 lo1 = *(const float4*)(rp + 32);
    float4 hi1 = *(const float4*)(rp + 36);

    const bf16x8 fBlo = __builtin_bit_cast(bf16x8, *(const uint4*)kF.blo[lane]);
    const bf16x8 fBhi = __builtin_bit_cast(bf16x8, *(const uint4*)kF.bhi[lane]);
    const bf16x8 fA2 = __builtin_bit_cast(bf16x8, *(const uint4*)kF.a2[lane]);

    uint4 ua0 = {pk2(lo0.x, lo0.y), pk2(lo0.z, lo0.w),
                 pk2(hi0.x, hi0.y), pk2(hi0.z, hi0.w)};
    uint4 ua1 = {pk2(lo1.x, lo1.y), pk2(lo1.z, lo1.w),
                 pk2(hi1.x, hi1.y), pk2(hi1.z, hi1.w)};
    const bf16x8 fA0 = __builtin_bit_cast(bf16x8, ua0);
    const bf16x8 fA1 = __builtin_bit_cast(bf16x8, ua1);

    // ---- stage A: W_b = X_b * G2n  (4 MFMAs; B const selects K half) ----
    const f32x4 z = {0.0f, 0.0f, 0.0f, 0.0f};
    f32x4 W0 = __builtin_amdgcn_mfma_f32_16x16x32_bf16(fA0, fBlo, z, 0, 0, 0);
    f32x4 W1 = __builtin_amdgcn_mfma_f32_16x16x32_bf16(fA0, fBhi, z, 0, 0, 0);
    f32x4 W2 = __builtin_amdgcn_mfma_f32_16x16x32_bf16(fA1, fBlo, z, 0, 0, 0);
    f32x4 W3 = __builtin_amdgcn_mfma_f32_16x16x32_bf16(fA1, fBhi, z, 0, 0, 0);

    // ---- transpose: D-layout (col v, rows 4q..4q+3) -> B-layout via LDS ----
    // W_cm[block][v][i] bf16, row pitch 48B (12 dwords): block base 192 dw.
    // Each row: dwords 0..7 hold i=0..15; dwords 8..11 are slack (unwritten).
    {
        const int wi = 12 * l15 + 2 * q;
        *(uint2*)(&Rw[wi]) = make_uint2(pk2(W0.x, W0.y), pk2(W0.z, W0.w));
        *(uint2*)(&Rw[192 + wi]) = make_uint2(pk2(W1.x, W1.y), pk2(W1.z, W1.w));
        *(uint2*)(&Rw[384 + wi]) = make_uint2(pk2(W2.x, W2.y), pk2(W2.z, W2.w));
        *(uint2*)(&Rw[576 + wi]) = make_uint2(pk2(W3.x, W3.y), pk2(W3.z, W3.w));
    }
    WAVE_LDS_FENCE();

    // B-frag read. k>=16 lanes (q=2,3) RE-READ the k<16 data (q&1): their
    // values are annihilated by fA2's exact zero padding, and re-reading
    // written data avoids 0*NaN from uninitialized LDS slack (R6 fix).
    bf16x8 fW[4];
    {
        const int ri = 12 * l15 + 4 * (q & 1);
#pragma unroll
        for (int b = 0; b < 4; ++b)
            fW[b] = __builtin_bit_cast(bf16x8, *(const uint4*)(&Rw[192 * b + ri]));
    }
    WAVE_LDS_FENCE();  // all B2 reads ordered before Ccm overlay-writes

    // ---- stage B: C_b = Gu * W_b  (A const, zero-padded K) ----
    // D: lane holds coeff[u = 4q + r][v = l15]; store column-major fp32:
    // Ccm[block][v][u] pitch 20 dwords, block base 324 dwords.
    {
#pragma unroll
        for (int b = 0; b < 4; ++b) {
            f32x4 C = __builtin_amdgcn_mfma_f32_16x16x32_bf16(fA2, fW[b], z, 0, 0, 0);
            *(f32x4*)(&R[324 * b + 20 * l15 + 4 * q]) = C;
        }
    }
    WAVE_LDS_FENCE();

    // ---- entropy (R4-verified): lane = (block q', column v=l15) ----
    {
        const float* C = &R[324 * q + 20 * l15];
        float c[16];
#pragma unroll
        for (int k = 0; k < 4; ++k) {
            float4 f = *(const float4*)(C + 4 * k);
            c[4 * k + 0] = f.x;
            c[4 * k + 1] = f.y;
            c[4 * k + 2] = f.z;
            c[4 * k + 3] = f.w;
        }
        const int v = l15;
        const int u_min = (v > 7) ? (16 - v) : (15 - v);

        float s = 0.0f;
#pragma unroll
        for (int u = 0; u < 16; ++u) s += (u >= u_min) ? c[u] : 0.0f;
#pragma unroll
        for (int m = 1; m <= 8; m <<= 1) s += __shfl_xor(s, m);
        const float mean = s * (1.0f / 128.0f);

        float a[16];
        float sq = 0.0f;
#pragma unroll
        for (int u = 0; u < 16; ++u) {
            float au = (c[u] < mean) ? 1e-12f : (fabsf(c[u]) + 1e-12f);
            a[u] = (u >= u_min) ? au : 0.0f;
            sq = fmaf(a[u], a[u], sq);
        }
#pragma unroll
        for (int m = 1; m <= 8; m <<= 1) sq += __shfl_xor(sq, m);
        const float inv = 1.0f / fmaxf(sqrtf(sq), 1e-12f);

        float e = 0.0f;
#pragma unroll
        for (int u = 0; u < 16; ++u) {
            float p = a[u] * inv;
            float term = p * __log2f(p);
            e += (u >= u_min) ? term : 0.0f;
        }
        // reduce within block (xor 1..8), then across the wave's 4 blocks
#pragma unroll
        for (int m = 1; m <= 32; m <<= 1) e += __shfl_xor(e, m);
        if (lane == 0) partials[(g << 2) + wave] = e;
    }
}

__global__ __launch_bounds__(1024) void reduce_partials(
    const float* __restrict__ partials, float* __restrict__ out) {
    __shared__ float s[16];
    float v = 0.0f;
    const float4* p4 = (const float4*)partials;
    for (int i = threadIdx.x; i < NPART / 4; i += 1024) {
        float4 f = p4[i];
        v += (f.x + f.y) + (f.z + f.w);
    }
#pragma unroll
    for (int m = 1; m <= 32; m <<= 1) v += __shfl_xor(v, m);
    if ((threadIdx.x & 63) == 0) s[threadIdx.x >> 6] = v;
    __syncthreads();
    if (threadIdx.x < 16) {
        float tot = s[threadIdx.x];
#pragma unroll
        for (int m = 1; m <= 8; m <<= 1) tot += __shfl_xor(tot, m);
        if (threadIdx.x == 0) out[0] = tot * (-1.0f / 98304.0f);
    }
}

extern "C" void kernel_launch(void* const* d_in, const int* in_sizes, int n_in,
                              void* d_out, int out_size, void* d_ws,
                              size_t ws_size, hipStream_t stream) {
    const float* x = (const float*)d_in[0];
    float* out = (float*)d_out;
    float* ws = (float*)d_ws;  // 24576 per-wave partials
    dct_entropy_kernel<<<NWG, 256, 0, stream>>>(x, ws);
    reduce_partials<<<1, 1024, 0, stream>>>(ws, out);
}